// Round 1
// baseline (504.643 us; speedup 1.0000x reference)
//
#include <hip/hip_runtime.h>
#include <hip/hip_bf16.h>

#define OUT_F 4096
#define IN_F 4096
#define MROWS 2048            // 4*512 batch rows
#define FFT_N 4096
#define FFT_LOG2 12

typedef short bf16x8 __attribute__((ext_vector_type(8)));
typedef float f32x4 __attribute__((ext_vector_type(4)));

// ---------------- scatter (last-write-wins, deterministic) ----------------
__global__ void winner_kernel(const int* __restrict__ idx, int* __restrict__ winner, int nnz) {
    int k = blockIdx.x * blockDim.x + threadIdx.x;
    if (k < nnz) atomicMax(&winner[idx[k]], k + 1);
}

__global__ void scatter_kernel(const int* __restrict__ idx, const float* __restrict__ re,
                               const float* __restrict__ im, const int* __restrict__ winner,
                               float2* __restrict__ A, int nnz) {
    int k = blockIdx.x * blockDim.x + threadIdx.x;
    if (k < nnz) {
        int id = idx[k];
        if (winner[id] == k + 1) {
            int u = id >> 12;            // row of [OUT_F, IN_F] spectrum
            int v = id & (IN_F - 1);     // col
            // store TRANSPOSED: A[v][u], so pass1 rows = ifft along axis 0
            A[(size_t)v * OUT_F + u] = make_float2(re[k], im[k]);
        }
    }
}

// ---------------- 4096-pt inverse FFT per row, in-place, in LDS ----------------
// Radix-2 DIT with bit-reversal. Inverse convention: exp(+2*pi*i*...), scale 1/N.
template <int REAL_OUT>
__global__ void __launch_bounds__(256) ifft_rows_kernel(float2* __restrict__ data,
                                                        __hip_bfloat16* __restrict__ wout) {
    __shared__ float2 buf[FFT_N];       // 32 KB
    __shared__ float2 tw[FFT_N / 2];    // 16 KB
    const int t = threadIdx.x;
    const size_t rowoff = (size_t)blockIdx.x * FFT_N;
    float2* __restrict__ g = data + rowoff;

    for (int j = t; j < FFT_N; j += 256) buf[j] = g[j];
    const double PI2N = 6.283185307179586476925286766559 / (double)FFT_N;
    for (int j = t; j < FFT_N / 2; j += 256) {
        double ds, dc;
        sincos(PI2N * (double)j, &ds, &dc);
        tw[j] = make_float2((float)dc, (float)ds);   // exp(+2*pi*i*j/N)
    }
    __syncthreads();

    // bit-reversal permutation (in-place, disjoint pair swaps)
    for (int j = t; j < FFT_N; j += 256) {
        int r = (int)(__brev((unsigned)j) >> (32 - FFT_LOG2));
        if (j < r) { float2 a = buf[j]; float2 b = buf[r]; buf[j] = b; buf[r] = a; }
    }
    __syncthreads();

    for (int stage = 1; stage <= FFT_LOG2; ++stage) {
        const int half = 1 << (stage - 1);
        const int len = half << 1;
        const int twsh = FFT_LOG2 - stage;
        #pragma unroll 1
        for (int jj = 0; jj < FFT_N / 2 / 256; ++jj) {
            int b = jj * 256 + t;
            int grp = b >> (stage - 1);
            int p = b & (half - 1);
            int i0 = grp * len + p;
            int i1 = i0 + half;
            float2 w = tw[p << twsh];
            float2 x1 = buf[i1];
            float2 x0 = buf[i0];
            float2 tt = make_float2(x1.x * w.x - x1.y * w.y, x1.x * w.y + x1.y * w.x);
            buf[i0] = make_float2(x0.x + tt.x, x0.y + tt.y);
            buf[i1] = make_float2(x0.x - tt.x, x0.y - tt.y);
        }
        __syncthreads();
    }

    const float scale = 1.0f / (float)FFT_N;
    if (REAL_OUT) {
        __hip_bfloat16* __restrict__ o = wout + rowoff;
        for (int j = t; j < FFT_N; j += 256) o[j] = __float2bfloat16(buf[j].x * scale);
    } else {
        for (int j = t; j < FFT_N; j += 256) {
            float2 v = buf[j];
            g[j] = make_float2(v.x * scale, v.y * scale);
        }
    }
}

// ---------------- in-place complex transpose (4096x4096 float2) ----------------
__global__ void transpose_kernel(float2* __restrict__ A) {
    const int bi = blockIdx.y, bj = blockIdx.x;
    if (bi > bj) return;
    __shared__ float2 tA[32][33];
    __shared__ float2 tB[32][33];
    const int tx = threadIdx.x;   // 0..31
    const int ty = threadIdx.y;   // 0..7
    #pragma unroll
    for (int k = 0; k < 4; ++k) {
        int r = ty + k * 8;
        tA[r][tx] = A[(size_t)(bi * 32 + r) * IN_F + bj * 32 + tx];
    }
    if (bi != bj) {
        #pragma unroll
        for (int k = 0; k < 4; ++k) {
            int r = ty + k * 8;
            tB[r][tx] = A[(size_t)(bj * 32 + r) * IN_F + bi * 32 + tx];
        }
    }
    __syncthreads();
    #pragma unroll
    for (int k = 0; k < 4; ++k) {
        int r = ty + k * 8;
        A[(size_t)(bj * 32 + r) * IN_F + bi * 32 + tx] = tA[tx][r];
    }
    if (bi != bj) {
        #pragma unroll
        for (int k = 0; k < 4; ++k) {
            int r = ty + k * 8;
            A[(size_t)(bi * 32 + r) * IN_F + bj * 32 + tx] = tB[tx][r];
        }
    }
}

// ---------------- f32 -> bf16 cast of x ----------------
__global__ void cast_x_kernel(const float4* __restrict__ x, ushort4* __restrict__ xb, int n4) {
    int i = blockIdx.x * blockDim.x + threadIdx.x;
    if (i < n4) {
        float4 v = x[i];
        __hip_bfloat16 a = __float2bfloat16(v.x);
        __hip_bfloat16 b = __float2bfloat16(v.y);
        __hip_bfloat16 c = __float2bfloat16(v.z);
        __hip_bfloat16 d = __float2bfloat16(v.w);
        ushort4 o;
        o.x = *reinterpret_cast<unsigned short*>(&a);
        o.y = *reinterpret_cast<unsigned short*>(&b);
        o.z = *reinterpret_cast<unsigned short*>(&c);
        o.w = *reinterpret_cast<unsigned short*>(&d);
        xb[i] = o;
    }
}

// ---------------- bf16 MFMA GEMM: out[M,N] = X[M,K] * W[N,K]^T + bias ----------------
__global__ void __launch_bounds__(256) gemm_kernel(const __hip_bfloat16* __restrict__ X,
                                                   const __hip_bfloat16* __restrict__ W,
                                                   const float* __restrict__ bias,
                                                   float* __restrict__ out) {
    __shared__ __align__(16) __hip_bfloat16 sA[128 * 32];   // 8 KB
    __shared__ __align__(16) __hip_bfloat16 sB[128 * 32];   // 8 KB
    const int tid = threadIdx.x;
    const int wv = tid >> 6;        // wave 0..3
    const int ln = tid & 63;
    const int m0 = blockIdx.y * 128;
    const int n0 = blockIdx.x * 128;
    const int wm = wv >> 1, wn = wv & 1;
    const int r16 = ln & 15, kg = ln >> 4;

    f32x4 acc[4][4];
    #pragma unroll
    for (int i = 0; i < 4; ++i)
        #pragma unroll
        for (int j = 0; j < 4; ++j) acc[i][j] = (f32x4){0.f, 0.f, 0.f, 0.f};

    for (int k0 = 0; k0 < IN_F; k0 += 32) {
        __syncthreads();
        #pragma unroll
        for (int c = 0; c < 2; ++c) {
            const int fc = (c * 4 + wv) * 64 + ln;   // chunk index 0..511
            const int row = fc >> 2;
            const int cc = fc & 3;
            const __hip_bfloat16* ga = X + (size_t)(m0 + row) * IN_F + k0 + cc * 8;
            __builtin_amdgcn_global_load_lds(
                (const __attribute__((address_space(1))) void*)ga,
                (__attribute__((address_space(3))) void*)(sA + (size_t)(c * 4 + wv) * 512),
                16, 0, 0);
            const __hip_bfloat16* gb = W + (size_t)(n0 + row) * IN_F + k0 + cc * 8;
            __builtin_amdgcn_global_load_lds(
                (const __attribute__((address_space(1))) void*)gb,
                (__attribute__((address_space(3))) void*)(sB + (size_t)(c * 4 + wv) * 512),
                16, 0, 0);
        }
        __syncthreads();

        bf16x8 af[4], bfr[4];
        #pragma unroll
        for (int i = 0; i < 4; ++i)
            af[i] = *reinterpret_cast<const bf16x8*>(&sA[(wm * 64 + i * 16 + r16) * 32 + kg * 8]);
        #pragma unroll
        for (int j = 0; j < 4; ++j)
            bfr[j] = *reinterpret_cast<const bf16x8*>(&sB[(wn * 64 + j * 16 + r16) * 32 + kg * 8]);
        #pragma unroll
        for (int i = 0; i < 4; ++i)
            #pragma unroll
            for (int j = 0; j < 4; ++j)
                acc[i][j] = __builtin_amdgcn_mfma_f32_16x16x32_bf16(af[i], bfr[j], acc[i][j], 0, 0, 0);
    }

    // epilogue: D[m][n], n = lane&15, m = (lane>>4)*4 + e
    #pragma unroll
    for (int i = 0; i < 4; ++i)
        #pragma unroll
        for (int j = 0; j < 4; ++j) {
            const int n = n0 + wn * 64 + j * 16 + r16;
            const float bs = bias[n];
            #pragma unroll
            for (int e = 0; e < 4; ++e) {
                const int m = m0 + wm * 64 + i * 16 + kg * 4 + e;
                out[(size_t)m * OUT_F + n] = acc[i][j][e] + bs;
            }
        }
}

extern "C" void kernel_launch(void* const* d_in, const int* in_sizes, int n_in,
                              void* d_out, int out_size, void* d_ws, size_t ws_size,
                              hipStream_t stream) {
    const float* x    = (const float*)d_in[0];
    const float* sre  = (const float*)d_in[1];
    const float* sim  = (const float*)d_in[2];
    const int*   sidx = (const int*)d_in[3];
    const float* bias = (const float*)d_in[4];
    const int nnz = in_sizes[1];
    float* out = (float*)d_out;

    char* ws = (char*)d_ws;
    // layout: A (spectrum, complex, in-place FFT/transpose): 128 MiB
    //         winner (int32, scatter only) 64 MiB — later aliased by W(bf16) + x(bf16)
    float2* A = (float2*)ws;                                           // 134217728 B
    int* winner = (int*)(ws + 134217728);                              // 67108864 B
    __hip_bfloat16* Wb = (__hip_bfloat16*)(ws + 134217728);            // 33554432 B (alias)
    __hip_bfloat16* Xb = (__hip_bfloat16*)(ws + 134217728 + 33554432); // 16777216 B (alias)

    hipMemsetAsync(A, 0, (size_t)134217728, stream);
    hipMemsetAsync(winner, 0, (size_t)67108864, stream);

    const int sb = (nnz + 255) / 256;
    winner_kernel<<<sb, 256, 0, stream>>>(sidx, winner, nnz);
    scatter_kernel<<<sb, 256, 0, stream>>>(sidx, sre, sim, winner, A, nnz);

    // pass 1: ifft along original axis 0 (rows of transposed spectrum), in-place
    ifft_rows_kernel<0><<<FFT_N, 256, 0, stream>>>(A, nullptr);
    // transpose so pass 2 is also row-wise
    transpose_kernel<<<dim3(128, 128), dim3(32, 8), 0, stream>>>(A);
    // pass 2: ifft along axis 1, real part -> bf16 weight [OUT_F][IN_F]
    ifft_rows_kernel<1><<<FFT_N, 256, 0, stream>>>(A, Wb);

    cast_x_kernel<<<(MROWS * IN_F / 4 + 255) / 256, 256, 0, stream>>>(
        (const float4*)x, (ushort4*)Xb, MROWS * IN_F / 4);

    gemm_kernel<<<dim3(OUT_F / 128, MROWS / 128), 256, 0, stream>>>(Xb, Wb, bias, out);
}

// Round 2
// 322.692 us; speedup vs baseline: 1.5639x; 1.5639x over previous
//
#include <hip/hip_runtime.h>
#include <hip/hip_bf16.h>

#define OUT_F 4096
#define IN_F 4096
#define MROWS 2048            // 4*512 batch rows
#define FFT_N 4096

typedef short bf16x8 __attribute__((ext_vector_type(8)));
typedef float f32x4 __attribute__((ext_vector_type(4)));

// ---------------- scatter (last-write-wins, deterministic) ----------------
__global__ void winner_kernel(const int* __restrict__ idx, int* __restrict__ winner, int nnz) {
    int k = blockIdx.x * blockDim.x + threadIdx.x;
    if (k < nnz) atomicMax(&winner[idx[k]], k + 1);
}

__global__ void scatter_kernel(const int* __restrict__ idx, const float* __restrict__ re,
                               const float* __restrict__ im, const int* __restrict__ winner,
                               float2* __restrict__ A, int nnz) {
    int k = blockIdx.x * blockDim.x + threadIdx.x;
    if (k < nnz) {
        int id = idx[k];
        if (winner[id] == k + 1) {
            int u = id >> 12;            // row of [OUT_F, IN_F] spectrum
            int v = id & (IN_F - 1);     // col
            // store TRANSPOSED: A[v][u], so pass1 rows = ifft along axis 0
            A[(size_t)v * OUT_F + u] = make_float2(re[k], im[k]);
        }
    }
}

// ---------------- 16-pt inverse FFT building blocks ----------------
__device__ __forceinline__ void bflyw(float2& a, float2& b, float wr, float wi) {
    float tr = b.x * wr - b.y * wi;
    float ti = b.x * wi + b.y * wr;
    b.x = a.x - tr; b.y = a.y - ti;
    a.x += tr; a.y += ti;
}
__device__ __forceinline__ void bfly1(float2& a, float2& b) {   // w = 1
    float tr = b.x, ti = b.y;
    b.x = a.x - tr; b.y = a.y - ti;
    a.x += tr; a.y += ti;
}
__device__ __forceinline__ void bflyI(float2& a, float2& b) {   // w = +i
    float tr = -b.y, ti = b.x;
    b.x = a.x - tr; b.y = a.y - ti;
    a.x += tr; a.y += ti;
}

#define C8f  0.70710678118654752f
#define C16f 0.92387953251128676f
#define S16f 0.38268343236508977f

// inverse 16-pt FFT (+i convention). Input loaded into bit-reversed slots, output natural.
__device__ __forceinline__ void fft16(float2 r[16]) {
    // stage 1 (w=1)
    bfly1(r[0], r[1]);  bfly1(r[2], r[3]);  bfly1(r[4], r[5]);   bfly1(r[6], r[7]);
    bfly1(r[8], r[9]);  bfly1(r[10], r[11]); bfly1(r[12], r[13]); bfly1(r[14], r[15]);
    // stage 2 (w = 1, i)
    bfly1(r[0], r[2]);  bflyI(r[1], r[3]);
    bfly1(r[4], r[6]);  bflyI(r[5], r[7]);
    bfly1(r[8], r[10]); bflyI(r[9], r[11]);
    bfly1(r[12], r[14]); bflyI(r[13], r[15]);
    // stage 3 (w = 1, w8, i, i*w8), w8 = e^{+i pi/4}
    bfly1(r[0], r[4]);  bflyw(r[1], r[5], C8f, C8f);  bflyI(r[2], r[6]);  bflyw(r[3], r[7], -C8f, C8f);
    bfly1(r[8], r[12]); bflyw(r[9], r[13], C8f, C8f); bflyI(r[10], r[14]); bflyw(r[11], r[15], -C8f, C8f);
    // stage 4 (w = w16^p), w16 = e^{+i pi/8}
    bfly1(r[0], r[8]);
    bflyw(r[1], r[9],  C16f, S16f);
    bflyw(r[2], r[10], C8f,  C8f);
    bflyw(r[3], r[11], S16f, C16f);
    bflyI(r[4], r[12]);
    bflyw(r[5], r[13], -S16f, C16f);
    bflyw(r[6], r[14], -C8f,  C8f);
    bflyw(r[7], r[15], -C16f, S16f);
}

// LDS XOR swizzle: spreads high address bits into bank bits; bijective on [0,4096)
__device__ __forceinline__ int swz(int a) { return a ^ ((a >> 5) & 31); }

// ---------------- 4096-pt inverse FFT per row: 3 phases of radix-16 ----------------
// Four-step decomposition: n = 256*n1 + n2, n2 = 16*m1 + m2; k = k1 + 16*j1 + 256*j2.
template <int REAL_OUT>
__global__ void __launch_bounds__(256) ifft_rows_kernel(float2* __restrict__ data,
                                                        __hip_bfloat16* __restrict__ wout) {
    __shared__ float bre[FFT_N];
    __shared__ float bim[FFT_N];
    const int t = threadIdx.x;
    const size_t rowoff = (size_t)blockIdx.x * FFT_N;
    const float2* __restrict__ g = data + rowoff;

    for (int j = t; j < FFT_N; j += 256) {
        float2 v = g[j];
        int a = swz(j);
        bre[a] = v.x; bim[a] = v.y;
    }
    __syncthreads();

    const int rv[16] = {0, 8, 4, 12, 2, 10, 6, 14, 1, 9, 5, 13, 3, 11, 7, 15};
    float2 r[16];

    // ---- phase 1: 16-pt over n1, one column n2 = t per thread ----
    #pragma unroll
    for (int n1 = 0; n1 < 16; ++n1) {
        int a = swz(256 * n1 + t);
        r[rv[n1]] = make_float2(bre[a], bim[a]);
    }
    fft16(r);
    {   // twiddle w4096^(k1*t)
        float s, c;
        sincosf((float)t * 1.5339807878856412e-3f, &s, &c);   // 2*pi/4096
        float2 w = make_float2(c, s), cur = make_float2(1.f, 0.f);
        #pragma unroll
        for (int k = 0; k < 16; ++k) {
            float xr = r[k].x * cur.x - r[k].y * cur.y;
            float xi = r[k].x * cur.y + r[k].y * cur.x;
            r[k].x = xr; r[k].y = xi;
            float nr = cur.x * w.x - cur.y * w.y;
            float ni = cur.x * w.y + cur.y * w.x;
            cur.x = nr; cur.y = ni;
        }
    }
    // per-thread read/write sets identical -> no sync needed before store
    #pragma unroll
    for (int k = 0; k < 16; ++k) {
        int a = swz(256 * k + t);
        bre[a] = r[k].x; bim[a] = r[k].y;
    }
    __syncthreads();

    // ---- phase 2: 16-pt over m1, thread owns (k1 = t>>4, m2 = t&15) ----
    const int k1 = t >> 4;
    const int lo = t & 15;
    const int base2 = 256 * k1 + lo;
    #pragma unroll
    for (int m1 = 0; m1 < 16; ++m1) {
        int a = swz(base2 + 16 * m1);
        r[rv[m1]] = make_float2(bre[a], bim[a]);
    }
    fft16(r);
    {   // twiddle w256^(j1*m2)
        float s, c;
        sincosf((float)lo * 2.45436926061702596e-2f, &s, &c); // 2*pi/256
        float2 w = make_float2(c, s), cur = make_float2(1.f, 0.f);
        #pragma unroll
        for (int k = 0; k < 16; ++k) {
            float xr = r[k].x * cur.x - r[k].y * cur.y;
            float xi = r[k].x * cur.y + r[k].y * cur.x;
            r[k].x = xr; r[k].y = xi;
            float nr = cur.x * w.x - cur.y * w.y;
            float ni = cur.x * w.y + cur.y * w.x;
            cur.x = nr; cur.y = ni;
        }
    }
    #pragma unroll
    for (int k = 0; k < 16; ++k) {
        int a = swz(base2 + 16 * k);
        bre[a] = r[k].x; bim[a] = r[k].y;
    }
    __syncthreads();

    // ---- phase 3: 16-pt over m2, thread owns (k1, j1 = t&15) ----
    const int base3 = 256 * k1 + 16 * lo;
    #pragma unroll
    for (int m = 0; m < 16; ++m) {
        int a = swz(base3 + m);
        r[rv[m]] = make_float2(bre[a], bim[a]);
    }
    fft16(r);
    __syncthreads();   // all reads done before digit-swap scatter overwrites

    const float scale = 1.0f / 4096.0f;
    const int outb = k1 + 16 * lo;          // k1 + 16*j1; + 256*j2 below
    #pragma unroll
    for (int j2 = 0; j2 < 16; ++j2) {
        int a = swz(outb + 256 * j2);
        bre[a] = r[j2].x * scale;
        if (!REAL_OUT) bim[a] = r[j2].y * scale;
    }
    __syncthreads();

    if (REAL_OUT) {
        __hip_bfloat16* __restrict__ o = wout + rowoff;
        for (int j = t; j < FFT_N; j += 256) o[j] = __float2bfloat16(bre[swz(j)]);
    } else {
        float2* __restrict__ og = data + rowoff;
        for (int j = t; j < FFT_N; j += 256) {
            int a = swz(j);
            og[j] = make_float2(bre[a], bim[a]);
        }
    }
}

// ---------------- in-place complex transpose (4096x4096 float2) ----------------
__global__ void transpose_kernel(float2* __restrict__ A) {
    const int bi = blockIdx.y, bj = blockIdx.x;
    if (bi > bj) return;
    __shared__ float2 tA[32][33];
    __shared__ float2 tB[32][33];
    const int tx = threadIdx.x;   // 0..31
    const int ty = threadIdx.y;   // 0..7
    #pragma unroll
    for (int k = 0; k < 4; ++k) {
        int r = ty + k * 8;
        tA[r][tx] = A[(size_t)(bi * 32 + r) * IN_F + bj * 32 + tx];
    }
    if (bi != bj) {
        #pragma unroll
        for (int k = 0; k < 4; ++k) {
            int r = ty + k * 8;
            tB[r][tx] = A[(size_t)(bj * 32 + r) * IN_F + bi * 32 + tx];
        }
    }
    __syncthreads();
    #pragma unroll
    for (int k = 0; k < 4; ++k) {
        int r = ty + k * 8;
        A[(size_t)(bj * 32 + r) * IN_F + bi * 32 + tx] = tA[tx][r];
    }
    if (bi != bj) {
        #pragma unroll
        for (int k = 0; k < 4; ++k) {
            int r = ty + k * 8;
            A[(size_t)(bi * 32 + r) * IN_F + bj * 32 + tx] = tB[tx][r];
        }
    }
}

// ---------------- f32 -> bf16 cast of x ----------------
__global__ void cast_x_kernel(const float4* __restrict__ x, ushort4* __restrict__ xb, int n4) {
    int i = blockIdx.x * blockDim.x + threadIdx.x;
    if (i < n4) {
        float4 v = x[i];
        __hip_bfloat16 a = __float2bfloat16(v.x);
        __hip_bfloat16 b = __float2bfloat16(v.y);
        __hip_bfloat16 c = __float2bfloat16(v.z);
        __hip_bfloat16 d = __float2bfloat16(v.w);
        ushort4 o;
        o.x = *reinterpret_cast<unsigned short*>(&a);
        o.y = *reinterpret_cast<unsigned short*>(&b);
        o.z = *reinterpret_cast<unsigned short*>(&c);
        o.w = *reinterpret_cast<unsigned short*>(&d);
        xb[i] = o;
    }
}

// ---------------- bf16 MFMA GEMM: out[M,N] = X[M,K] * W[N,K]^T + bias ----------------
__global__ void __launch_bounds__(256) gemm_kernel(const __hip_bfloat16* __restrict__ X,
                                                   const __hip_bfloat16* __restrict__ W,
                                                   const float* __restrict__ bias,
                                                   float* __restrict__ out) {
    __shared__ __align__(16) __hip_bfloat16 sA[128 * 32];   // 8 KB
    __shared__ __align__(16) __hip_bfloat16 sB[128 * 32];   // 8 KB
    const int tid = threadIdx.x;
    const int wv = tid >> 6;        // wave 0..3
    const int ln = tid & 63;
    const int m0 = blockIdx.y * 128;
    const int n0 = blockIdx.x * 128;
    const int wm = wv >> 1, wn = wv & 1;
    const int r16 = ln & 15, kg = ln >> 4;

    f32x4 acc[4][4];
    #pragma unroll
    for (int i = 0; i < 4; ++i)
        #pragma unroll
        for (int j = 0; j < 4; ++j) acc[i][j] = (f32x4){0.f, 0.f, 0.f, 0.f};

    for (int k0 = 0; k0 < IN_F; k0 += 32) {
        __syncthreads();
        #pragma unroll
        for (int c = 0; c < 2; ++c) {
            const int fc = (c * 4 + wv) * 64 + ln;   // chunk index 0..511
            const int row = fc >> 2;
            const int cc = fc & 3;
            const __hip_bfloat16* ga = X + (size_t)(m0 + row) * IN_F + k0 + cc * 8;
            __builtin_amdgcn_global_load_lds(
                (const __attribute__((address_space(1))) void*)ga,
                (__attribute__((address_space(3))) void*)(sA + (size_t)(c * 4 + wv) * 512),
                16, 0, 0);
            const __hip_bfloat16* gb = W + (size_t)(n0 + row) * IN_F + k0 + cc * 8;
            __builtin_amdgcn_global_load_lds(
                (const __attribute__((address_space(1))) void*)gb,
                (__attribute__((address_space(3))) void*)(sB + (size_t)(c * 4 + wv) * 512),
                16, 0, 0);
        }
        __syncthreads();

        bf16x8 af[4], bfr[4];
        #pragma unroll
        for (int i = 0; i < 4; ++i)
            af[i] = *reinterpret_cast<const bf16x8*>(&sA[(wm * 64 + i * 16 + r16) * 32 + kg * 8]);
        #pragma unroll
        for (int j = 0; j < 4; ++j)
            bfr[j] = *reinterpret_cast<const bf16x8*>(&sB[(wn * 64 + j * 16 + r16) * 32 + kg * 8]);
        #pragma unroll
        for (int i = 0; i < 4; ++i)
            #pragma unroll
            for (int j = 0; j < 4; ++j)
                acc[i][j] = __builtin_amdgcn_mfma_f32_16x16x32_bf16(af[i], bfr[j], acc[i][j], 0, 0, 0);
    }

    // epilogue: D[m][n], n = lane&15, m = (lane>>4)*4 + e
    #pragma unroll
    for (int i = 0; i < 4; ++i)
        #pragma unroll
        for (int j = 0; j < 4; ++j) {
            const int n = n0 + wn * 64 + j * 16 + r16;
            const float bs = bias[n];
            #pragma unroll
            for (int e = 0; e < 4; ++e) {
                const int m = m0 + wm * 64 + i * 16 + kg * 4 + e;
                out[(size_t)m * OUT_F + n] = acc[i][j][e] + bs;
            }
        }
}

extern "C" void kernel_launch(void* const* d_in, const int* in_sizes, int n_in,
                              void* d_out, int out_size, void* d_ws, size_t ws_size,
                              hipStream_t stream) {
    const float* x    = (const float*)d_in[0];
    const float* sre  = (const float*)d_in[1];
    const float* sim  = (const float*)d_in[2];
    const int*   sidx = (const int*)d_in[3];
    const float* bias = (const float*)d_in[4];
    const int nnz = in_sizes[1];
    float* out = (float*)d_out;

    char* ws = (char*)d_ws;
    // layout: A (spectrum, complex, in-place FFT/transpose): 128 MiB
    //         winner (int32, scatter only) 64 MiB — later aliased by W(bf16) + x(bf16)
    float2* A = (float2*)ws;                                           // 134217728 B
    int* winner = (int*)(ws + 134217728);                              // 67108864 B
    __hip_bfloat16* Wb = (__hip_bfloat16*)(ws + 134217728);            // 33554432 B (alias)
    __hip_bfloat16* Xb = (__hip_bfloat16*)(ws + 134217728 + 33554432); // 16777216 B (alias)

    hipMemsetAsync(A, 0, (size_t)134217728, stream);
    hipMemsetAsync(winner, 0, (size_t)67108864, stream);

    const int sb = (nnz + 255) / 256;
    winner_kernel<<<sb, 256, 0, stream>>>(sidx, winner, nnz);
    scatter_kernel<<<sb, 256, 0, stream>>>(sidx, sre, sim, winner, A, nnz);

    // pass 1: ifft along original axis 0 (rows of transposed spectrum), in-place
    ifft_rows_kernel<0><<<FFT_N, 256, 0, stream>>>(A, nullptr);
    // transpose so pass 2 is also row-wise
    transpose_kernel<<<dim3(128, 128), dim3(32, 8), 0, stream>>>(A);
    // pass 2: ifft along axis 1, real part -> bf16 weight [OUT_F][IN_F]
    ifft_rows_kernel<1><<<FFT_N, 256, 0, stream>>>(A, Wb);

    cast_x_kernel<<<(MROWS * IN_F / 4 + 255) / 256, 256, 0, stream>>>(
        (const float4*)x, (ushort4*)Xb, MROWS * IN_F / 4);

    gemm_kernel<<<dim3(OUT_F / 128, MROWS / 128), 256, 0, stream>>>(Xb, Wb, bias, out);
}